// Round 1
// 74.139 us; speedup vs baseline: 1.0635x; 1.0635x over previous
//
#include <hip/hip_runtime.h>

// Median blur 5x5, reflect pad, fp32, (4,3,512,512).
// v5: retile 256x8 -> 128x16 (halo 1.52x -> 1.29x), vectorized staging
// (aligned float2 global loads + ds_write_b128, 3 tasks/thread instead of
// 13 scalar iterations, reflect math per 4-col group). Order-stat core
// (proven absmax 0 in v4) kept bit-identical.

#define TW 16
#define TH 16
#define PX 8
#define TILEW (TW * PX)    // 128
#define LDSW (TILEW + 4)   // 132 floats; row stride 528 B = 33*16 (b128-aligned)
#define LDSH (TH + 4)      // 20
#define NCOL (PX + 4)      // 12 columns per thread
#define NG (LDSW / 4)      // 33 float4 groups per LDS row
#define NTASK (LDSH * NG)  // 660 staging tasks per block
#define NTHREADS (TW * TH) // 256

__device__ __forceinline__ float mn(float a, float b) { return fminf(a, b); }
__device__ __forceinline__ float mx(float a, float b) { return fmaxf(a, b); }
__device__ __forceinline__ float mn3(float a, float b, float c) { return fminf(a, fminf(b, c)); }
__device__ __forceinline__ float mx3(float a, float b, float c) { return fmaxf(a, fmaxf(b, c)); }
__device__ __forceinline__ float md3(float a, float b, float c) {
    return __builtin_amdgcn_fmed3f(a, b, c);  // single v_med3_f32; NaN-free input
}

// Full sort of 5 (ascending): sort3 + sort2 + exact merge order stats.
__device__ __forceinline__ void sort5(float& v0, float& v1, float& v2, float& v3, float& v4) {
    float a1 = mn3(v0, v1, v2), a2 = md3(v0, v1, v2), a3 = mx3(v0, v1, v2);
    float b1 = mn(v3, v4), b2 = mx(v3, v4);
    float t1 = mx(a1, b1), u1 = mn(a2, b2), u2 = mn(a3, b2);
    float s0 = mn(a1, b1);
    float s1 = mn(t1, u1);
    float s2 = md3(a2, t1, u2);
    float s3 = mx(u2, mx(a2, b1));
    float s4 = mx(a3, b2);
    v0 = s0; v1 = s1; v2 = s2; v3 = s3; v4 = s4;
}

// ranks 2,3,4 of 5 (ascending o2<=o3<=o4)
__device__ __forceinline__ void top3of5(float v0, float v1, float v2, float v3, float v4,
                                        float& o2, float& o3, float& o4) {
    float a2 = md3(v0, v1, v2), a3 = mx3(v0, v1, v2);
    float a1 = mn3(v0, v1, v2);
    float b1 = mn(v3, v4), b2 = mx(v3, v4);
    float t1 = mx(a1, b1), u2 = mn(a3, b2);
    o2 = md3(a2, t1, u2);
    o3 = mx(u2, mx(a2, b1));
    o4 = mx(a3, b2);
}

// ranks 1,2,3 of 5
__device__ __forceinline__ void mid3of5(float v0, float v1, float v2, float v3, float v4,
                                        float& o1, float& o2, float& o3) {
    float a1 = mn3(v0, v1, v2), a2 = md3(v0, v1, v2), a3 = mx3(v0, v1, v2);
    float b1 = mn(v3, v4), b2 = mx(v3, v4);
    float t1 = mx(a1, b1), u1 = mn(a2, b2), u2 = mn(a3, b2);
    o1 = mn(t1, u1);
    o2 = md3(a2, t1, u2);
    o3 = mx(u2, mx(a2, b1));
}

// ranks 0,1,2 of 5
__device__ __forceinline__ void bot3of5(float v0, float v1, float v2, float v3, float v4,
                                        float& o0, float& o1, float& o2) {
    float a1 = mn3(v0, v1, v2), a2 = md3(v0, v1, v2), a3 = mx3(v0, v1, v2);
    float b1 = mn(v3, v4), b2 = mx(v3, v4);
    float t1 = mx(a1, b1), u1 = mn(a2, b2), u2 = mn(a3, b2);
    o0 = mn(a1, b1);
    o1 = mn(t1, u1);
    o2 = md3(a2, t1, u2);
}

// ranks 3,4 of 5 (o3<=o4)
__device__ __forceinline__ void top2of5(float v0, float v1, float v2, float v3, float v4,
                                        float& o3, float& o4) {
    float p1 = mn(v0, v1), q1 = mx(v0, v1);
    float p2 = mn(v2, v3), q2 = mx(v2, v3);
    float xx2 = mx(q1, q2);
    float xx1 = mx3(p1, p2, mn(q1, q2));
    o4 = mx(xx2, v4);
    o3 = md3(xx1, xx2, v4);
}

// ranks 0,1 of 5
__device__ __forceinline__ void bot2of5(float v0, float v1, float v2, float v3, float v4,
                                        float& o0, float& o1) {
    float p1 = mn(v0, v1), q1 = mx(v0, v1);
    float p2 = mn(v2, v3), q2 = mx(v2, v3);
    float zz1 = mn(p1, p2);
    float zz2 = mn3(q1, q2, mx(p1, p2));
    o0 = mn(zz1, v4);
    o1 = md3(zz1, zz2, v4);
}

// ranks 2,3 of 4 (o2<=o3)
__device__ __forceinline__ void top2of4(float v0, float v1, float v2, float v3,
                                        float& o2, float& o3) {
    float p1 = mn(v0, v1), q1 = mx(v0, v1);
    float p2 = mn(v2, v3), q2 = mx(v2, v3);
    o3 = mx(q1, q2);
    o2 = mx3(p1, p2, mn(q1, q2));
}

// ranks 0,1 of 4
__device__ __forceinline__ void bot2of4(float v0, float v1, float v2, float v3,
                                        float& o0, float& o1) {
    float p1 = mn(v0, v1), q1 = mx(v0, v1);
    float p2 = mn(v2, v3), q2 = mx(v2, v3);
    o0 = mn(p1, p2);
    o1 = mn3(q1, q2, mx(p1, p2));
}

__global__ __launch_bounds__(NTHREADS) void median5_kernel(
    const float* __restrict__ in, float* __restrict__ out, int H, int W) {
    __shared__ float sm[LDSH][LDSW];

    const int plane = blockIdx.z;
    const float* ip = in + (size_t)plane * H * W;
    float* op = out + (size_t)plane * H * W;

    const int tx = threadIdx.x, ty = threadIdx.y;
    const int ox = blockIdx.x * TILEW, oy = blockIdx.y * TH;
    const int tid = ty * TW + tx;

    // Vectorized staging: each task stages one 4-col group of one LDS row.
    // LDS col L = k*4 maps to global col gx = ox + L - 2 (aligned to 8 B in
    // global, 16 B in LDS). Only groups touching the image x-edge (k==0 on
    // left block, k==NG-1 on right block) take the scalar reflect path.
#pragma unroll
    for (int t0 = 0; t0 < NTASK; t0 += NTHREADS) {
        int t = t0 + tid;
        if (t < NTASK) {
            int rr = t / NG;
            int k = t - rr * NG;
            int gy = oy + rr - 2;
            gy = gy < 0 ? -gy : (gy >= H ? 2 * H - 2 - gy : gy);
            int gx = ox + k * 4 - 2;
            float4 v;
            if (gx >= 0 && gx + 3 < W) {
                const float2* p2 = (const float2*)(ip + (size_t)gy * W + gx);
                float2 lo = p2[0], hi = p2[1];
                v.x = lo.x; v.y = lo.y; v.z = hi.x; v.w = hi.y;
            } else {
                int g0 = gx, g1 = gx + 1, g2 = gx + 2, g3 = gx + 3;
                g0 = g0 < 0 ? -g0 : (g0 >= W ? 2 * W - 2 - g0 : g0);
                g1 = g1 < 0 ? -g1 : (g1 >= W ? 2 * W - 2 - g1 : g1);
                g2 = g2 < 0 ? -g2 : (g2 >= W ? 2 * W - 2 - g2 : g2);
                g3 = g3 < 0 ? -g3 : (g3 >= W ? 2 * W - 2 - g3 : g3);
                const float* rowp = ip + (size_t)gy * W;
                v.x = rowp[g0]; v.y = rowp[g1]; v.z = rowp[g2]; v.w = rowp[g3];
            }
            *(float4*)&sm[rr][k * 4] = v;  // ds_write_b128, 16B-aligned
        }
    }
    __syncthreads();

    // 12 columns x 5 rows into registers (three float4 per row, 16B aligned).
    // Bank check: lane addr bank = (4*(ty+dy) + 8*tx) mod 32 covers all 8
    // 4-bank groups with 8 lanes each -> conflict-free-optimal b128 reads.
    float f[5][NCOL];
#pragma unroll
    for (int dy = 0; dy < 5; ++dy) {
        const float4* base = (const float4*)&sm[ty + dy][tx * PX];
        float4 v0 = base[0], v1 = base[1], v2 = base[2];
        f[dy][0] = v0.x; f[dy][1] = v0.y; f[dy][2] = v0.z; f[dy][3] = v0.w;
        f[dy][4] = v1.x; f[dy][5] = v1.y; f[dy][6] = v1.z; f[dy][7] = v1.w;
        f[dy][8] = v2.x; f[dy][9] = v2.y; f[dy][10] = v2.z; f[dy][11] = v2.w;
    }

    // Sort the 12 columns along y (shared by the 8 output pixels).
#pragma unroll
    for (int c = 0; c < NCOL; ++c)
        sort5(f[0][c], f[1][c], f[2][c], f[3][c], f[4][c]);

    float res[PX];
#pragma unroll
    for (int p = 0; p < PX; ++p) {
        // 13 doubly-sorted candidates from the col-sorted 5x5 window.
        float a, b;
        top2of5(f[0][p], f[0][p + 1], f[0][p + 2], f[0][p + 3], f[0][p + 4], a, b);
        float c1, d1, e1;
        top3of5(f[1][p], f[1][p + 1], f[1][p + 2], f[1][p + 3], f[1][p + 4], c1, d1, e1);
        float f2, g2, h2;
        mid3of5(f[2][p], f[2][p + 1], f[2][p + 2], f[2][p + 3], f[2][p + 4], f2, g2, h2);
        float i3, j3, k3;
        bot3of5(f[3][p], f[3][p + 1], f[3][p + 2], f[3][p + 3], f[3][p + 4], i3, j3, k3);
        float l4, m4;
        bot2of5(f[4][p], f[4][p + 1], f[4][p + 2], f[4][p + 3], f[4][p + 4], l4, m4);

        // 13 -> 7 -> med3.
        float x1, x2;
        top2of4(a, c1, f2, i3, x1, x2);
        float y1, y2, y3;
        mid3of5(b, d1, g2, j3, l4, y1, y2, y3);
        float z1, z2;
        bot2of4(e1, h2, k3, m4, z1, z2);

        res[p] = md3(mx(x1, y1), md3(x2, y2, z1), mn(y3, z2));
    }

    // Two float4 stores (out row is 16B aligned at ox + tx*PX).
    float4 o0, o1;
    o0.x = res[0]; o0.y = res[1]; o0.z = res[2]; o0.w = res[3];
    o1.x = res[4]; o1.y = res[5]; o1.z = res[6]; o1.w = res[7];
    float4* obase = (float4*)&op[(size_t)(oy + ty) * W + ox + tx * PX];
    obase[0] = o0;
    obase[1] = o1;
}

extern "C" void kernel_launch(void* const* d_in, const int* in_sizes, int n_in,
                              void* d_out, int out_size, void* d_ws, size_t ws_size,
                              hipStream_t stream) {
    const float* img = (const float*)d_in[0];
    float* out = (float*)d_out;
    const int H = 512, W = 512;
    const int planes = in_sizes[0] / (H * W);  // 12
    dim3 block(TW, TH, 1);
    dim3 grid(W / TILEW, H / TH, planes);
    median5_kernel<<<grid, block, 0, stream>>>(img, out, H, W);
}

// Round 2
// 72.864 us; speedup vs baseline: 1.0821x; 1.0175x over previous
//
#include <hip/hip_runtime.h>

// Median blur 5x5, reflect pad, fp32, (4,3,512,512).
// v6: 2 output rows per thread (sort4 of 4 shared rows + 5-instr sorted
// insert per window = 20 instr/col/2rows vs 32), tile 128x32 (halo 1.16x),
// staging via global_load_lds width=16 (task count padded to 5*256 so every
// DMA issues fully active; x-reflect edge groups fixed up by a scalar pass
// behind a second block-uniform barrier). Order-stat merge core unchanged
// (proven absmax 0).

#define TW 16
#define TH 16
#define PX 8
#define RY 2
#define TILEW (TW * PX)     // 128
#define TILEH (TH * RY)     // 32
#define LDSW (TILEW + 4)    // 132 floats; row stride 528 B = 33*16
#define LDSH (TILEH + 4)    // 36
#define NG (LDSW / 4)       // 33 float4 groups per row
#define NTASK (LDSH * NG)   // 1188 real staging tasks
#define NTASK_PAD 1280      // 5 * 256: all gload_lds iterations fully active
#define NTHREADS (TW * TH)  // 256
#define NCOL (PX + 4)       // 12 columns per thread

__device__ __forceinline__ float mn(float a, float b) { return fminf(a, b); }
__device__ __forceinline__ float mx(float a, float b) { return fmaxf(a, b); }
__device__ __forceinline__ float mn3(float a, float b, float c) { return fminf(a, fminf(b, c)); }
__device__ __forceinline__ float mx3(float a, float b, float c) { return fmaxf(a, fmaxf(b, c)); }
__device__ __forceinline__ float md3(float a, float b, float c) {
    return __builtin_amdgcn_fmed3f(a, b, c);  // single v_med3_f32; NaN-free input
}
__device__ __forceinline__ void cs(float& a, float& b) {
    float lo = mn(a, b), hi = mx(a, b); a = lo; b = hi;
}
__device__ __forceinline__ int refl(int x, int n) {
    return x < 0 ? -x : (x >= n ? 2 * n - 2 - x : x);
}

// ranks 2,3,4 of 5 (ascending o2<=o3<=o4)
__device__ __forceinline__ void top3of5(float v0, float v1, float v2, float v3, float v4,
                                        float& o2, float& o3, float& o4) {
    float a2 = md3(v0, v1, v2), a3 = mx3(v0, v1, v2);
    float a1 = mn3(v0, v1, v2);
    float b1 = mn(v3, v4), b2 = mx(v3, v4);
    float t1 = mx(a1, b1), u2 = mn(a3, b2);
    o2 = md3(a2, t1, u2);
    o3 = mx(u2, mx(a2, b1));
    o4 = mx(a3, b2);
}

// ranks 1,2,3 of 5
__device__ __forceinline__ void mid3of5(float v0, float v1, float v2, float v3, float v4,
                                        float& o1, float& o2, float& o3) {
    float a1 = mn3(v0, v1, v2), a2 = md3(v0, v1, v2), a3 = mx3(v0, v1, v2);
    float b1 = mn(v3, v4), b2 = mx(v3, v4);
    float t1 = mx(a1, b1), u1 = mn(a2, b2), u2 = mn(a3, b2);
    o1 = mn(t1, u1);
    o2 = md3(a2, t1, u2);
    o3 = mx(u2, mx(a2, b1));
}

// ranks 0,1,2 of 5
__device__ __forceinline__ void bot3of5(float v0, float v1, float v2, float v3, float v4,
                                        float& o0, float& o1, float& o2) {
    float a1 = mn3(v0, v1, v2), a2 = md3(v0, v1, v2), a3 = mx3(v0, v1, v2);
    float b1 = mn(v3, v4), b2 = mx(v3, v4);
    float t1 = mx(a1, b1), u1 = mn(a2, b2), u2 = mn(a3, b2);
    o0 = mn(a1, b1);
    o1 = mn(t1, u1);
    o2 = md3(a2, t1, u2);
}

// ranks 3,4 of 5 (o3<=o4)
__device__ __forceinline__ void top2of5(float v0, float v1, float v2, float v3, float v4,
                                        float& o3, float& o4) {
    float p1 = mn(v0, v1), q1 = mx(v0, v1);
    float p2 = mn(v2, v3), q2 = mx(v2, v3);
    float xx2 = mx(q1, q2);
    float xx1 = mx3(p1, p2, mn(q1, q2));
    o4 = mx(xx2, v4);
    o3 = md3(xx1, xx2, v4);
}

// ranks 0,1 of 5
__device__ __forceinline__ void bot2of5(float v0, float v1, float v2, float v3, float v4,
                                        float& o0, float& o1) {
    float p1 = mn(v0, v1), q1 = mx(v0, v1);
    float p2 = mn(v2, v3), q2 = mx(v2, v3);
    float zz1 = mn(p1, p2);
    float zz2 = mn3(q1, q2, mx(p1, p2));
    o0 = mn(zz1, v4);
    o1 = md3(zz1, zz2, v4);
}

// ranks 2,3 of 4 (o2<=o3)
__device__ __forceinline__ void top2of4(float v0, float v1, float v2, float v3,
                                        float& o2, float& o3) {
    float p1 = mn(v0, v1), q1 = mx(v0, v1);
    float p2 = mn(v2, v3), q2 = mx(v2, v3);
    o3 = mx(q1, q2);
    o2 = mx3(p1, p2, mn(q1, q2));
}

// ranks 0,1 of 4
__device__ __forceinline__ void bot2of4(float v0, float v1, float v2, float v3,
                                        float& o0, float& o1) {
    float p1 = mn(v0, v1), q1 = mx(v0, v1);
    float p2 = mn(v2, v3), q2 = mx(v2, v3);
    o0 = mn(p1, p2);
    o1 = mn3(q1, q2, mx(p1, p2));
}

// Pruned 13-candidate merge of 5 column-sorted 5-tuples, 8 sliding windows.
// F_r[c] = rank r (ascending) of column c. Proven absmax 0 (v4/v5).
__device__ __forceinline__ void merge8(const float (&F0)[NCOL], const float (&F1)[NCOL],
                                       const float (&F2)[NCOL], const float (&F3)[NCOL],
                                       const float (&F4)[NCOL], float (&res)[PX]) {
#pragma unroll
    for (int p = 0; p < PX; ++p) {
        float a, b;
        top2of5(F0[p], F0[p + 1], F0[p + 2], F0[p + 3], F0[p + 4], a, b);
        float c1, d1, e1;
        top3of5(F1[p], F1[p + 1], F1[p + 2], F1[p + 3], F1[p + 4], c1, d1, e1);
        float f2, g2, h2;
        mid3of5(F2[p], F2[p + 1], F2[p + 2], F2[p + 3], F2[p + 4], f2, g2, h2);
        float i3, j3, k3;
        bot3of5(F3[p], F3[p + 1], F3[p + 2], F3[p + 3], F3[p + 4], i3, j3, k3);
        float l4, m4;
        bot2of5(F4[p], F4[p + 1], F4[p + 2], F4[p + 3], F4[p + 4], l4, m4);

        float x1, x2;
        top2of4(a, c1, f2, i3, x1, x2);
        float y1, y2, y3;
        mid3of5(b, d1, g2, j3, l4, y1, y2, y3);
        float z1, z2;
        bot2of4(e1, h2, k3, m4, z1, z2);

        res[p] = md3(mx(x1, y1), md3(x2, y2, z1), mn(y3, z2));
    }
}

__global__ __launch_bounds__(NTHREADS, 3) void median5_kernel(
    const float* __restrict__ in, float* __restrict__ out, int H, int W) {
    // Flat LDS; real data occupies the first NTASK*4 floats (36 rows x 132),
    // padded tasks land in the tail slack so every gload_lds is fully active.
    __shared__ float smf[NTASK_PAD * 4 + 32];

    const int plane = blockIdx.z;
    const float* ip = in + (size_t)plane * H * W;
    float* op = out + (size_t)plane * H * W;

    const int tx = threadIdx.x, ty = threadIdx.y;
    const int ox = blockIdx.x * TILEW, oy = blockIdx.y * TILEH;
    const int tid = ty * TW + tx;

    // --- Staging: one 16B group per task, direct global->LDS DMA. ---
    // Task t covers LDS floats [t*4, t*4+4) = row rr = t/NG, cols 4k-2..4k+1
    // (global x). Per-lane LDS dest = base + lane*16 exactly matches the HW
    // wave-uniform-base + lane*size rule. x-edge groups get a clamped (safe,
    // contiguous) source here and are corrected by the fixup pass below.
#pragma unroll
    for (int t0 = 0; t0 < NTASK_PAD; t0 += NTHREADS) {
        int t = t0 + tid;
        int rr = t / NG;
        int k = t - rr * NG;
        int gy = refl(oy + rr - 2, H);
        int gx = ox + 4 * k - 2;
        int gxc = gx < 0 ? 0 : (gx > W - 4 ? W - 4 : gx);
        const float* src = ip + (size_t)gy * W + gxc;
        __builtin_amdgcn_global_load_lds(
            (const __attribute__((address_space(1))) void*)src,
            (__attribute__((address_space(3))) void*)&smf[t * 4], 16, 0, 0);
    }
    __syncthreads();  // drains vmcnt(0): all DMAs complete

    // --- x-reflect fixup (only blocks touching image x-edges). ---
    const bool leftb = (ox == 0);
    const bool rightb = (ox + TILEW >= W);
    if (leftb || rightb) {  // block-uniform branch
        if (tid < LDSH) {
            int rr = tid;
            int gy = refl(oy + rr - 2, H);
            const float* rowp = ip + (size_t)gy * W;
            if (leftb) {
                // group k=0: cols -2,-1,0,1 -> reflect 2,1,0,1
                smf[rr * LDSW + 0] = rowp[2];
                smf[rr * LDSW + 1] = rowp[1];
                smf[rr * LDSW + 2] = rowp[0];
                smf[rr * LDSW + 3] = rowp[1];
            } else {
                // group k=NG-1: cols W-2,W-1,W,W+1 -> W-2,W-1,W-2,W-3
                smf[rr * LDSW + 4 * (NG - 1) + 0] = rowp[W - 2];
                smf[rr * LDSW + 4 * (NG - 1) + 1] = rowp[W - 1];
                smf[rr * LDSW + 4 * (NG - 1) + 2] = rowp[W - 2];
                smf[rr * LDSW + 4 * (NG - 1) + 3] = rowp[W - 3];
            }
        }
        __syncthreads();
    }

    // --- Load 6 rows x 12 cols (three b128 per row). ---
    float T0[NCOL], T1[NCOL], T2[NCOL], T3[NCOL], R0[NCOL], R5[NCOL];
    const int baseRow = RY * ty;
#pragma unroll
    for (int dy = 0; dy < 6; ++dy) {
        const float4* b = (const float4*)&smf[(baseRow + dy) * LDSW + tx * PX];
        float4 v0 = b[0], v1 = b[1], v2 = b[2];
        float tmp[NCOL] = {v0.x, v0.y, v0.z, v0.w, v1.x, v1.y, v1.z, v1.w,
                           v2.x, v2.y, v2.z, v2.w};
#pragma unroll
        for (int c = 0; c < NCOL; ++c) {
            if (dy == 0) R0[c] = tmp[c];
            else if (dy == 1) T0[c] = tmp[c];
            else if (dy == 2) T1[c] = tmp[c];
            else if (dy == 3) T2[c] = tmp[c];
            else if (dy == 4) T3[c] = tmp[c];
            else R5[c] = tmp[c];
        }
    }

    // --- sort4 of the 4 shared rows, per column (shared by both windows). ---
#pragma unroll
    for (int c = 0; c < NCOL; ++c) {
        cs(T0[c], T1[c]); cs(T2[c], T3[c]);
        cs(T0[c], T2[c]); cs(T1[c], T3[c]);
        cs(T1[c], T2[c]);
    }

    // --- Window A (output row oy + 2ty): insert R0 into sorted T. ---
    float A0[NCOL], A1[NCOL], A2[NCOL], A3[NCOL], A4[NCOL];
#pragma unroll
    for (int c = 0; c < NCOL; ++c) {
        A0[c] = mn(T0[c], R0[c]);
        A1[c] = md3(T0[c], T1[c], R0[c]);
        A2[c] = md3(T1[c], T2[c], R0[c]);
        A3[c] = md3(T2[c], T3[c], R0[c]);
        A4[c] = mx(T3[c], R0[c]);
    }
    float res[PX];
    merge8(A0, A1, A2, A3, A4, res);
    {
        float4 o0, o1;
        o0.x = res[0]; o0.y = res[1]; o0.z = res[2]; o0.w = res[3];
        o1.x = res[4]; o1.y = res[5]; o1.z = res[6]; o1.w = res[7];
        float4* obase = (float4*)&op[(size_t)(oy + RY * ty) * W + ox + tx * PX];
        obase[0] = o0;
        obase[1] = o1;
    }

    // --- Window B (output row oy + 2ty + 1): insert R5 into sorted T. ---
#pragma unroll
    for (int c = 0; c < NCOL; ++c) {
        A0[c] = mn(T0[c], R5[c]);
        A1[c] = md3(T0[c], T1[c], R5[c]);
        A2[c] = md3(T1[c], T2[c], R5[c]);
        A3[c] = md3(T2[c], T3[c], R5[c]);
        A4[c] = mx(T3[c], R5[c]);
    }
    merge8(A0, A1, A2, A3, A4, res);
    {
        float4 o0, o1;
        o0.x = res[0]; o0.y = res[1]; o0.z = res[2]; o0.w = res[3];
        o1.x = res[4]; o1.y = res[5]; o1.z = res[6]; o1.w = res[7];
        float4* obase = (float4*)&op[(size_t)(oy + RY * ty + 1) * W + ox + tx * PX];
        obase[0] = o0;
        obase[1] = o1;
    }
}

extern "C" void kernel_launch(void* const* d_in, const int* in_sizes, int n_in,
                              void* d_out, int out_size, void* d_ws, size_t ws_size,
                              hipStream_t stream) {
    const float* img = (const float*)d_in[0];
    float* out = (float*)d_out;
    const int H = 512, W = 512;
    const int planes = in_sizes[0] / (H * W);  // 12
    dim3 block(TW, TH, 1);
    dim3 grid(W / TILEW, H / TILEH, planes);
    median5_kernel<<<grid, block, 0, stream>>>(img, out, H, W);
}